// Round 3
// baseline (146.024 us; speedup 1.0000x reference)
//
#include <hip/hip_runtime.h>

// TFMBSLinear forward on MI355X:
//   out[b][o] = sum_k sign(x[b][k]) * sign(w[o][k]) + bias[o]
// R6: R5 with the K-loop count FIXED (R5 bug: ran 16 K-tiles instead of 8,
// reading past each 32 KiB strip -> absmax 246; M/N tile change never
// affects K extent: K=2048 = 8 tiles x 256 elems = strip 32768 B).
// Structure: 128x128 deep-pipelined MXFP4 GEMM, 64 KiB LDS -> 2 blocks/CU,
// grid 1024 = 4 rounds/CU so C-write epilogues overlap co-resident block's
// MFMA phases (R4's 256x256 was 1 block/CU -> serialized 10.6us C-drain).
// qx/qw layout unchanged (operand-tiled fp4, lane = (k-half)*32 + (row&31)):
// ds_read_b128 lane*16-contiguous (zero bank conflicts), global_load_lds
// wave-uniform-base + lane*16. Per phase: {4 frag ds_reads || 2 gload_lds
// for tile t+1 -> vmcnt(6) -> barrier -> setprio(1), 4 MFMA, setprio(0) ->
// barrier}; vmcnt never 0 in main loop (next-needed pair = oldest of 4
// outstanding pairs). Math exact (fp4 {0,+-1}, fp32 accum, |sum| <= 2048)
// -> absmax 0.

typedef int   intx4    __attribute__((ext_vector_type(4)));
typedef int   intx8    __attribute__((ext_vector_type(8)));
typedef float floatx16 __attribute__((ext_vector_type(16)));

static constexpr int M = 8192;   // batch
static constexpr int N = 2048;   // out features
static constexpr int K = 2048;   // in features
static constexpr int KB = K / 2; // 1024 packed bytes per row
static constexpr int BM = 128, BN = 128;

// ---------------- quantize: fp32 -> sign fp4, tiled operand order ----------
__device__ __forceinline__ unsigned nib(float v) {
    // +1.0 -> 0x2, -1.0 -> 0xA, 0 -> 0x0 (e2m1)
    unsigned u = __float_as_uint(v);
    return (v != 0.0f) ? (0x2u | ((u >> 28) & 0x8u)) : 0u;
}

__device__ __forceinline__ unsigned pack8(const float4& a, const float4& b) {
    return  nib(a.x)        | (nib(a.y) << 4)  | (nib(a.z) << 8)  | (nib(a.w) << 12)
         | (nib(b.x) << 16) | (nib(b.y) << 20) | (nib(b.z) << 24) | (nib(b.w) << 28);
}

// chunk g (16B out) -> s,c,h,r: g = s*2048 + c*64 + h*32 + r
// source: row m = s*32+r, floats [(c*2+h)*32 .. +32)
__global__ __launch_bounds__(256) void quant_tile(
    const float* __restrict__ x, const float* __restrict__ w,
    uint4* __restrict__ qx, uint4* __restrict__ qw, int nx, int ntot)
{
    int g = blockIdx.x * 256 + threadIdx.x;
    if (g >= ntot) return;
    const float* src; uint4* dst; int gg;
    if (g < nx) { gg = g; src = x; dst = qx; }
    else        { gg = g - nx; src = w; dst = qw; }
    const int r = gg & 31, h = (gg >> 5) & 1, c = (gg >> 6) & 31, s = gg >> 11;
    const int m = s * 32 + r;
    const float4* p = (const float4*)(src + (size_t)m * K + (c * 2 + h) * 32);
    uint4 o;
    o.x = pack8(p[0], p[1]);
    o.y = pack8(p[2], p[3]);
    o.z = pack8(p[4], p[5]);
    o.w = pack8(p[6], p[7]);
    dst[gg] = o;   // coalesced: consecutive threads -> consecutive 16B
}

// ---------------- MXFP4 ternary GEMM, C = A * B^T + bias ----------------
__device__ __forceinline__ intx8 ext4(intx4 v) {
    return __builtin_shufflevector(v, v, 0, 1, 2, 3, -1, -1, -1, -1);
}

#define MFMA_(A_, B_, C_) __builtin_amdgcn_mfma_scale_f32_32x32x64_f8f6f4( \
    ext4(A_), ext4(B_), C_, 4, 4, 0, 127, 0, 127)

#define GLDS(g_, l_) __builtin_amdgcn_global_load_lds(                      \
    (const __attribute__((address_space(1))) void*)(g_),                    \
    (__attribute__((address_space(3))) void*)(l_), 16, 0, 0)

#define MFMA4()                               \
    acc[0][0] = MFMA_(a0, b0, acc[0][0]);     \
    acc[0][1] = MFMA_(a0, b1, acc[0][1]);     \
    acc[1][0] = MFMA_(a1, b0, acc[1][0]);     \
    acc[1][1] = MFMA_(a1, b1, acc[1][1])

#define FRAGS(FO)                                         \
    intx4 a0 = *(const intx4*)(fA + (FO));                \
    intx4 a1 = *(const intx4*)(fA + (FO) + 4096);         \
    intx4 b0 = *(const intx4*)(fB + (FO));                \
    intx4 b1 = *(const intx4*)(fB + (FO) + 4096)

__global__ __launch_bounds__(256, 2) void tgemm_fp4_128(
    const char* __restrict__ A,
    const char* __restrict__ B,
    const float* __restrict__ bias,
    float* __restrict__ C)
{
    // sA: [buf][strip 0..3][kstep 0..3][1024] at smem+0      (32 KiB)
    // sB: same at smem+32768                                  (32 KiB)
    __shared__ char smem[65536];

    const int tid  = threadIdx.x;
    const int wave = tid >> 6;
    const int lane = tid & 63;
    const int l32  = lane & 31;
    const int half = lane >> 5;

    // XCD-bijective mapping: 1024 blocks, xcd = bi&7 owns 8 M-panels (1 MB)
    // x 16 N-panels (2 MB) -> resident in its 4 MB L2.
    const int bi  = blockIdx.x;
    const int idx = bi >> 3;
    const int bm  = (((bi & 7) << 3) + (idx & 7)) << 7;
    const int bn  = (idx >> 3) << 7;

    // Staging: wave w stages A strip (bm/32+w) and B strip (bn/32+w).
    // Global src carries lane*16; LDS dst is wave-uniform (HW adds lane*16).
    const char* gA = A + ((size_t)(bm >> 5) + wave) * 32768 + lane * 16;
    const char* gB = B + ((size_t)(bn >> 5) + wave) * 32768 + lane * 16;
    char* stA = smem + wave * 4096;            // + buf + c*1024
    char* stB = smem + 32768 + wave * 4096;

    const int wm = (wave & 1) * 64;
    const int wn = (wave >> 1) * 64;

    // Fragment bases: A strips wm/32 + i, B strips wn/32 + j; + buf + c*1024.
    const char* fA = smem + (wm >> 5) * 4096 + lane * 16;
    const char* fB = smem + 32768 + (wn >> 5) * 4096 + lane * 16;

    floatx16 acc[2][2] = {};

    // ---- prologue: stage tile 0 (8 loads, kstep-ordered pairs)
    #pragma unroll
    for (int c = 0; c < 4; ++c) {
        GLDS(gA + c * 1024, stA + c * 1024);
        GLDS(gB + c * 1024, stB + c * 1024);
    }
    asm volatile("s_waitcnt vmcnt(6)" ::: "memory");
    __builtin_amdgcn_s_barrier();

    // ---- main loop: K-tiles 0..6 compute, prefetch tile t+1 (8 tiles total)
    for (int t = 0; t < 7; ++t) {
        const int buf  = (t & 1) * 16384;
        const int xbuf = buf ^ 16384;
        const char* ga = gA + (size_t)(t + 1) * 4096;
        const char* gb = gB + (size_t)(t + 1) * 4096;
        #pragma unroll
        for (int c = 0; c < 4; ++c) {
            FRAGS(buf + c * 1024);
            GLDS(ga + c * 1024, stA + xbuf + c * 1024);
            GLDS(gb + c * 1024, stB + xbuf + c * 1024);
            // oldest 2 of 8 outstanding = pair for next-needed kstep
            asm volatile("s_waitcnt vmcnt(6)" ::: "memory");
            __builtin_amdgcn_s_barrier();
            __builtin_amdgcn_s_setprio(1);
            MFMA4();
            __builtin_amdgcn_s_setprio(0);
            __builtin_amdgcn_s_barrier();
        }
    }

    // ---- tail: K-tile 7 (buf=16384), no prefetch; step vmcnt down 4->2->0
    {
        const int buf = 16384;
        #pragma unroll
        for (int c = 0; c < 4; ++c) {
            FRAGS(buf + c * 1024);
            if (c == 0) { asm volatile("s_waitcnt vmcnt(4)" ::: "memory"); __builtin_amdgcn_s_barrier(); }
            if (c == 1) { asm volatile("s_waitcnt vmcnt(2)" ::: "memory"); __builtin_amdgcn_s_barrier(); }
            if (c == 2) { asm volatile("s_waitcnt vmcnt(0)" ::: "memory"); __builtin_amdgcn_s_barrier(); }
            __builtin_amdgcn_s_setprio(1);
            MFMA4();
            __builtin_amdgcn_s_setprio(0);
            if (c < 3) __builtin_amdgcn_s_barrier();
        }
    }

    // ---- epilogue: 32x32 C/D: col = lane&31, row = (reg&3)+8*(reg>>2)+4*half
    const int cn0 = bn + wn + l32;
    const float bc0 = bias[cn0];
    const float bc1 = bias[cn0 + 32];
    const int rbase = bm + wm + 4 * half;

    #pragma unroll
    for (int i = 0; i < 2; ++i) {
        #pragma unroll
        for (int r = 0; r < 16; ++r) {
            const int row = rbase + 32 * i + (r & 3) + 8 * (r >> 2);
            C[(size_t)row * N + cn0]      = acc[i][0][r] + bc0;
            C[(size_t)row * N + cn0 + 32] = acc[i][1][r] + bc1;
        }
    }
}

extern "C" void kernel_launch(void* const* d_in, const int* in_sizes, int n_in,
                              void* d_out, int out_size, void* d_ws, size_t ws_size,
                              hipStream_t stream) {
    const float* x    = (const float*)d_in[0];   // [M,K] fp32
    const float* w    = (const float*)d_in[1];   // [N,K] fp32
    const float* bias = (const float*)d_in[2];   // [N]   fp32
    float* out = (float*)d_out;                  // [M,N] fp32

    // workspace: qx (8 MB) then qw (2 MB), operand-tiled packed fp4
    char* qx = (char*)d_ws;
    char* qw = qx + (size_t)M * KB;

    const int nx   = (M * KB) / 16;              // 524,288 chunks
    const int ntot = nx + (N * KB) / 16;         // 655,360
    quant_tile<<<ntot / 256, 256, 0, stream>>>(
        x, w, (uint4*)qx, (uint4*)qw, nx, ntot);

    tgemm_fp4_128<<<dim3((M / BM) * (N / BN)), dim3(256), 0, stream>>>(
        qx, qw, bias, out);
}

// Round 4
// 140.671 us; speedup vs baseline: 1.0381x; 1.0381x over previous
//
#include <hip/hip_runtime.h>

// TFMBSLinear forward on MI355X:
//   out[b][o] = sum_k sign(x[b][k]) * sign(w[o][k]) + bias[o]
// R7: 256x128 block, 4 waves (wave tile 128x64, acc[4][2] -> 8 MFMA/phase,
// same density as R4-256sq) with 48 KiB LDS -> 2 async blocks/CU (grid 512).
// R6 post-mortem: 128sq halved per-phase MFMA density -> 2x barrier tax per
// output; R7 keeps density AND gets cross-block overlap (epilogue C-write +
// phase stalls of one block hide under the co-resident block's MFMAs).
// Phase body: {vmcnt(3) -> barrier -> 6 frag ds_reads -> 3 gload_lds for
// tile t+1 -> setprio(1) 8 MFMA setprio(0)} -- ONE barrier/phase (32 total).
// Drain math (per wave, 3 loads/phase): at phase p top, outstanding = 6
// (p-1's 3 + p-2's 3); vmcnt(3) drains p-2's 3 = exactly the kstep FRAGS
// reads this phase. Write-after-read: region (buf,c) rewritten at p was last
// read at p-2, completed before barrier at p-1. Tail: vmcnt(3) then vmcnt(0).
// qx/qw layout unchanged (operand-tiled fp4, lane = (k-half)*32 + (row&31)):
// ds_read_b128 lane*16-contiguous (zero bank conflicts), gload_lds
// wave-uniform-base + lane*16. Math exact (fp4 {0,+-1}, fp32 accum,
// |sum| <= 2048) -> absmax 0.

typedef int   intx4    __attribute__((ext_vector_type(4)));
typedef int   intx8    __attribute__((ext_vector_type(8)));
typedef float floatx16 __attribute__((ext_vector_type(16)));

static constexpr int M = 8192;   // batch
static constexpr int N = 2048;   // out features
static constexpr int K = 2048;   // in features
static constexpr int KB = K / 2; // 1024 packed bytes per row
static constexpr int BM = 256, BN = 128;

// ---------------- quantize: fp32 -> sign fp4, tiled operand order ----------
__device__ __forceinline__ unsigned nib(float v) {
    // +1.0 -> 0x2, -1.0 -> 0xA, 0 -> 0x0 (e2m1)
    unsigned u = __float_as_uint(v);
    return (v != 0.0f) ? (0x2u | ((u >> 28) & 0x8u)) : 0u;
}

__device__ __forceinline__ unsigned pack8(const float4& a, const float4& b) {
    return  nib(a.x)        | (nib(a.y) << 4)  | (nib(a.z) << 8)  | (nib(a.w) << 12)
         | (nib(b.x) << 16) | (nib(b.y) << 20) | (nib(b.z) << 24) | (nib(b.w) << 28);
}

// chunk g (16B out) -> s,c,h,r: g = s*2048 + c*64 + h*32 + r
// source: row m = s*32+r, floats [(c*2+h)*32 .. +32)
__global__ __launch_bounds__(256) void quant_tile(
    const float* __restrict__ x, const float* __restrict__ w,
    uint4* __restrict__ qx, uint4* __restrict__ qw, int nx, int ntot)
{
    int g = blockIdx.x * 256 + threadIdx.x;
    if (g >= ntot) return;
    const float* src; uint4* dst; int gg;
    if (g < nx) { gg = g; src = x; dst = qx; }
    else        { gg = g - nx; src = w; dst = qw; }
    const int r = gg & 31, h = (gg >> 5) & 1, c = (gg >> 6) & 31, s = gg >> 11;
    const int m = s * 32 + r;
    const float4* p = (const float4*)(src + (size_t)m * K + (c * 2 + h) * 32);
    uint4 o;
    o.x = pack8(p[0], p[1]);
    o.y = pack8(p[2], p[3]);
    o.z = pack8(p[4], p[5]);
    o.w = pack8(p[6], p[7]);
    dst[gg] = o;   // coalesced: consecutive threads -> consecutive 16B
}

// ---------------- MXFP4 ternary GEMM, C = A * B^T + bias ----------------
__device__ __forceinline__ intx8 ext4(intx4 v) {
    return __builtin_shufflevector(v, v, 0, 1, 2, 3, -1, -1, -1, -1);
}

#define MFMA_(A_, B_, C_) __builtin_amdgcn_mfma_scale_f32_32x32x64_f8f6f4( \
    ext4(A_), ext4(B_), C_, 4, 4, 0, 127, 0, 127)

#define GLDS(g_, l_) __builtin_amdgcn_global_load_lds(                      \
    (const __attribute__((address_space(1))) void*)(g_),                    \
    (__attribute__((address_space(3))) void*)(l_), 16, 0, 0)

#define MFMA8()                               \
    acc[0][0] = MFMA_(a0, b0, acc[0][0]);     \
    acc[0][1] = MFMA_(a0, b1, acc[0][1]);     \
    acc[1][0] = MFMA_(a1, b0, acc[1][0]);     \
    acc[1][1] = MFMA_(a1, b1, acc[1][1]);     \
    acc[2][0] = MFMA_(a2, b0, acc[2][0]);     \
    acc[2][1] = MFMA_(a2, b1, acc[2][1]);     \
    acc[3][0] = MFMA_(a3, b0, acc[3][0]);     \
    acc[3][1] = MFMA_(a3, b1, acc[3][1])

// A region (strip s, kstep c) at sA + s*2048 + c*1024; sB likewise at +16384.
#define FRAGS(BUF_, C_)                                                     \
    intx4 a0 = *(const intx4*)(smem + (BUF_) + fAo          + (C_) * 1024); \
    intx4 a1 = *(const intx4*)(smem + (BUF_) + fAo + 2048   + (C_) * 1024); \
    intx4 a2 = *(const intx4*)(smem + (BUF_) + fAo + 4096   + (C_) * 1024); \
    intx4 a3 = *(const intx4*)(smem + (BUF_) + fAo + 6144   + (C_) * 1024); \
    intx4 b0 = *(const intx4*)(smem + (BUF_) + fBo          + (C_) * 1024); \
    intx4 b1 = *(const intx4*)(smem + (BUF_) + fBo + 2048   + (C_) * 1024)

__global__ __launch_bounds__(256, 2) void tgemm_fp4_256x128(
    const char* __restrict__ A,
    const char* __restrict__ B,
    const float* __restrict__ bias,
    float* __restrict__ C)
{
    // per buffer: sA 8 strips x 2 ksteps x 1KB = 16KB, sB 4x2x1KB = 8KB
    // buf b at smem + b*24576 (sB at +16384). Total 48 KiB -> 2 blocks/CU.
    __shared__ char smem[49152];

    const int tid  = threadIdx.x;
    const int wave = tid >> 6;
    const int lane = tid & 63;
    const int l32  = lane & 31;
    const int half = lane >> 5;

    // XCD-bijective: 512 blocks; xcd = bi&7 owns 4 A-panels (1 MB) x all 16
    // B-panels (2 MB) -> 3 MB resident in its 4 MB L2.
    const int bi    = blockIdx.x;
    const int local = bi >> 3;                      // 0..63
    const int bm    = ((bi & 7) * 4 + (local & 3)) * 256;
    const int bn    = (local >> 2) * 128;

    // Staging: wave w stages A strips 2w,2w+1 and B strip w (3 gloads/phase).
    // Strip = 32 ksteps x 1KB; global kstep g = 2t+c at byte g*1024.
    const char* gA0 = A + ((size_t)(bm >> 5) + 2 * wave) * 32768 + lane * 16;
    const char* gA1 = gA0 + 32768;
    const char* gB0 = B + ((size_t)(bn >> 5) + wave) * 32768 + lane * 16;
    const int stA0 = (2 * wave) * 2048;             // + buf + c*1024
    const int stA1 = stA0 + 2048;
    const int stB0 = 16384 + wave * 2048;

    const int wm = (wave & 1) * 128;
    const int wn = (wave >> 1) * 64;
    const int fAo = (wm >> 5) * 2048 + lane * 16;           // + buf + i*2048 + c*1024
    const int fBo = 16384 + (wn >> 5) * 2048 + lane * 16;   // + buf + j*2048 + c*1024

    floatx16 acc[4][2] = {};

    // ---- prologue: stage tile 0 (ksteps 0,1) into buf 0, kstep-grouped
    #pragma unroll
    for (int c = 0; c < 2; ++c) {
        GLDS(gA0 + c * 1024, smem + stA0 + c * 1024);
        GLDS(gA1 + c * 1024, smem + stA1 + c * 1024);
        GLDS(gB0 + c * 1024, smem + stB0 + c * 1024);
    }

    // ---- main loop: K-tiles 0..14 (2 ksteps each), prefetch tile t+1
    #pragma unroll
    for (int t = 0; t < 15; ++t) {
        const int buf  = (t & 1) * 24576;
        const int xbuf = buf ^ 24576;
        #pragma unroll
        for (int c = 0; c < 2; ++c) {
            // drain the 3 loads issued 2 phases ago == this phase's data
            asm volatile("s_waitcnt vmcnt(3)" ::: "memory");
            __builtin_amdgcn_s_barrier();
            FRAGS(buf, c);
            const int g = (t + 1) * 2 + c;
            GLDS(gA0 + g * 1024, smem + xbuf + stA0 + c * 1024);
            GLDS(gA1 + g * 1024, smem + xbuf + stA1 + c * 1024);
            GLDS(gB0 + g * 1024, smem + xbuf + stB0 + c * 1024);
            __builtin_amdgcn_s_setprio(1);
            MFMA8();
            __builtin_amdgcn_s_setprio(0);
        }
    }

    // ---- tail: K-tile 15 (buf = 24576), no prefetch
    {
        {
            asm volatile("s_waitcnt vmcnt(3)" ::: "memory");
            __builtin_amdgcn_s_barrier();
            FRAGS(24576, 0);
            __builtin_amdgcn_s_setprio(1);
            MFMA8();
            __builtin_amdgcn_s_setprio(0);
        }
        {
            asm volatile("s_waitcnt vmcnt(0)" ::: "memory");
            __builtin_amdgcn_s_barrier();
            FRAGS(24576, 1);
            __builtin_amdgcn_s_setprio(1);
            MFMA8();
            __builtin_amdgcn_s_setprio(0);
        }
    }

    // ---- epilogue: 32x32 C/D: col = lane&31, row = (reg&3)+8*(reg>>2)+4*half
    const int cn0 = bn + wn + l32;
    const float bc0 = bias[cn0];
    const float bc1 = bias[cn0 + 32];
    const int rbase = bm + wm + 4 * half;

    #pragma unroll
    for (int i = 0; i < 4; ++i) {
        #pragma unroll
        for (int r = 0; r < 16; ++r) {
            const int row = rbase + 32 * i + (r & 3) + 8 * (r >> 2);
            C[(size_t)row * N + cn0]      = acc[i][0][r] + bc0;
            C[(size_t)row * N + cn0 + 32] = acc[i][1][r] + bc1;
        }
    }
}

extern "C" void kernel_launch(void* const* d_in, const int* in_sizes, int n_in,
                              void* d_out, int out_size, void* d_ws, size_t ws_size,
                              hipStream_t stream) {
    const float* x    = (const float*)d_in[0];   // [M,K] fp32
    const float* w    = (const float*)d_in[1];   // [N,K] fp32
    const float* bias = (const float*)d_in[2];   // [N]   fp32
    float* out = (float*)d_out;                  // [M,N] fp32

    // workspace: qx (8 MB) then qw (2 MB), operand-tiled packed fp4
    char* qx = (char*)d_ws;
    char* qw = qx + (size_t)M * KB;

    const int nx   = (M * KB) / 16;              // 524,288 chunks
    const int ntot = nx + (N * KB) / 16;         // 655,360
    quant_tile<<<ntot / 256, 256, 0, stream>>>(
        x, w, (uint4*)qx, (uint4*)qw, nx, ntot);

    tgemm_fp4_256x128<<<dim3((M / BM) * (N / BN)), dim3(256), 0, stream>>>(
        qx, qw, bias, out);
}